// Round 5
// baseline (2237.273 us; speedup 1.0000x reference)
//
#include <hip/hip_runtime.h>

typedef unsigned short u16;
typedef unsigned int u32;
typedef __attribute__((ext_vector_type(4))) float f32x4;
typedef __attribute__((ext_vector_type(8))) short s16x8;

#define DEVI static __device__ __forceinline__

// B=2, S=2048, E=2048, H=16, D=128, MP=4, local=512; qkv cols: [q(512) v(512) k(512)] x4
// k-rope fused into QKV-GEMM epilogue; q-rope (+ (1/sqrt(128))*log2(e) scale) fused into
// attention prologue; softmax in exp2 domain.

#define ROPE_C (-13.287712379549449f / 32.0f)  // -log2(10000)/32
#define QSCALE 0.12751743f                     // log2(e)/sqrt(128)

DEVI u16 f2bf(float f) {
  u32 u = __float_as_uint(f);
  return (u16)((u + 0x7FFFu + ((u >> 16) & 1u)) >> 16);  // round-to-nearest-even
}
DEVI float bf2f(u16 h) { return __uint_as_float(((u32)h) << 16); }

DEVI void async_copy16(const u16* g, u16* l) {
  // dest = wave-uniform LDS base + lane*16 (gfx950 global_load_lds_dwordx4)
  __builtin_amdgcn_global_load_lds((__attribute__((address_space(1))) void*)g,
                                   (__attribute__((address_space(3))) void*)l, 16, 0, 0);
}

// fused fp32->bf16 cast of all three inputs
__global__ __launch_bounds__(256) void cast3_kernel(
    const float* __restrict__ s0, u16* __restrict__ d0, int n0,
    const float* __restrict__ s1, u16* __restrict__ d1, int n1,
    const float* __restrict__ s2, u16* __restrict__ d2, int n2) {
  int i = blockIdx.x * 256 + threadIdx.x;
  const float* s;
  u16* d;
  if (i < n0) {
    s = s0; d = d0;
  } else if (i < n0 + n1) {
    s = s1; d = d1; i -= n0;
  } else if (i < n0 + n1 + n2) {
    s = s2; d = d2; i -= n0 + n1;
  } else {
    return;
  }
  const float4 v = ((const float4*)s)[i];
  ushort4 o;
  o.x = f2bf(v.x); o.y = f2bf(v.y); o.z = f2bf(v.z); o.w = f2bf(v.w);
  ((ushort4*)d)[i] = o;
}

// C[m,n] = sum_k A[m,k]*B[n,k]; A,B row-major bf16, K contiguous (B^T GEMM).
// 128x128 tile, BK=32, 4 waves 2x2 of 64x64, 16x16x32 MFMA, 4x4 frags/wave.
// NT n-tiles per block processed sequentially; stage of next tile's k=0,32 issued
// before the previous tile's epilogue (stores cover the DMA latency -> no cold
// prologue on tile 2; halves per-block fixed costs). 3-deep LDS pipeline,
// vmcnt(4) + raw s_barrier in steady state, vmcnt(0) at tile boundaries.
// EPI=0: C fp32 store. EPI=1: scatter qkv -> q[B,H,S,D], k(roped)[B,H,S,D], v^T[B,H,D,S].
template <int EPI, int NT>
__global__ __launch_bounds__(256, 3) void gemm_bt_kernel(
    const u16* __restrict__ A, const u16* __restrict__ Bm, int K, int N,
    float* __restrict__ C, u16* __restrict__ qo, u16* __restrict__ ko, u16* __restrict__ vo) {
  __shared__ __attribute__((aligned(16))) u16 As[3][128 * 32];  // 8KB each
  __shared__ __attribute__((aligned(16))) u16 Bs[3][128 * 32];  // 8KB each
  const int tid = threadIdx.x;
  const int w = tid >> 6, lane = tid & 63;
  const int quad = lane >> 4, l16 = lane & 15;
  const int wrow = (w >> 1) * 64, wcol = (w & 1) * 64;
  const long tileM = (long)blockIdx.y * 128;
  const long tileN0 = (long)blockIdx.x * (128 * NT);

  f32x4 acc[4][4];
#pragma unroll
  for (int i = 0; i < 4; ++i)
#pragma unroll
    for (int j = 0; j < 4; ++j) acc[i][j] = f32x4{0.f, 0.f, 0.f, 0.f};

  // staging: wave w covers tile rows [w*32, w*32+32) in two 16-row chunks.
  // lane -> row r0+(lane>>2), LDS chunk pos p=lane&3; global col chunk = p ^ ((row>>1)&3).
  const u16* aptr[2];
  const u16* bptr[2];
  int ldso[2];
#pragma unroll
  for (int c = 0; c < 2; ++c) {
    const int r0 = (w * 2 + c) * 16;
    const int row = r0 + (lane >> 2);
    const int colsw = (((lane & 3) ^ ((row >> 1) & 3)) << 3);
    aptr[c] = A + (tileM + row) * (long)K + colsw;
    bptr[c] = Bm + (tileN0 + row) * (long)K + colsw;
    ldso[c] = r0 * 32;
  }

  auto stage = [&](int s0, int buf) {
    // virtual k s0 in [0, NT*K); maps to (n-tile, k)
    const int ka = (s0 >= K) ? s0 - K : s0;
    const long boff = (s0 >= K) ? (long)ka + 128L * K : (long)ka;  // +128 B-rows for tile 2
#pragma unroll
    for (int c = 0; c < 2; ++c) {
      async_copy16(aptr[c] + ka, &As[buf][ldso[c]]);
      async_copy16(bptr[c] + boff, &Bs[buf][ldso[c]]);
    }
  };

  auto epilogue = [&](long tileN) {
    const int b = (int)(tileM >> 11);  // 128-row tile never straddles batch (2048%128==0)
#pragma unroll
    for (int i = 0; i < 4; ++i) {
#pragma unroll
      for (int j = 0; j < 4; ++j) {
        const int rowb = (int)((tileM + wrow + i * 16 + quad * 4) & 2047);  // s of reg 0
        if (EPI == 0) {
#pragma unroll
          for (int r = 0; r < 4; ++r) {
            const long row = tileM + wrow + i * 16 + quad * 4 + r;
            C[row * N + tileN + wcol + j * 16 + l16] = acc[i][j][r];
          }
        } else {
          const long col0 = tileN + wcol + j * 16;  // wave-uniform base col of this frag
          const int mp = (int)(col0 / 1536);
          const int cc0 = (int)(col0 - (long)mp * 1536);
          const int part = cc0 >> 9;         // 0:q 1:v 2:k (uniform: 16-col group in one chunk)
          const int idx0 = cc0 & 511;
          const int head = mp * 4 + (idx0 >> 7);
          const int dim0 = idx0 & 127;       // base dim; lane dim = dim0 + l16
          const int dim = dim0 + l16;
          const long bh = (long)(b * 16 + head);
          if (part == 1) {
            // v stored transposed [B,H,D,S]
#pragma unroll
            for (int r = 0; r < 4; ++r)
              vo[(bh * 128 + dim) * 2048 + rowb + r] = f2bf(acc[i][j][r]);
          } else {
            float y[4];
            if (part == 2 && dim0 < 64) {
              // rope: pair partner is adjacent lane (col parity == l16 parity)
              const int jj = dim >> 1;  // same for both lanes of the pair
              const float inv = exp2f((float)jj * ROPE_C);
#pragma unroll
              for (int r = 0; r < 4; ++r) {
                const float v = acc[i][j][r];
                const float pv = __shfl_xor(v, 1, 64);
                const float ang = (float)(rowb + r) * inv;
                const float sn = sinf(ang), cs = cosf(ang);
                y[r] = (l16 & 1) ? (v * cs + pv * sn) : (v * cs - pv * sn);
              }
            } else {
#pragma unroll
              for (int r = 0; r < 4; ++r) y[r] = acc[i][j][r];
            }
            u16* dst = (part == 0) ? qo : ko;
#pragma unroll
            for (int r = 0; r < 4; ++r)
              dst[(bh * 2048 + rowb + r) * 128 + dim] = f2bf(y[r]);
          }
        }
      }
    }
  };

  stage(0, 0);
  stage(32, 1);

  // read-side swizzled chunk position (lane-constant)
  const int psw = (quad ^ ((l16 >> 1) & 3)) << 3;

  const int KK = K * NT;
  int bt = 0;
  for (int kk = 0; kk < KK; kk += 32) {
    const bool bound = (kk + 32 >= KK) || (NT == 2 && kk == K);
    if (bound)
      __builtin_amdgcn_s_waitcnt(0x0f70);  // vmcnt(0): boundary (stores also count)
    else
      __builtin_amdgcn_s_waitcnt(0x0f74);  // vmcnt(4): tile kk landed, kk+32 in flight
    __builtin_amdgcn_s_barrier();          // raw barrier: no compiler-forced drain
    if (kk + 64 < KK) stage(kk + 64, bt == 0 ? 2 : bt - 1);

    s16x8 af[4], bfr[4];
#pragma unroll
    for (int i = 0; i < 4; ++i)
      af[i] = *(const s16x8*)(&As[bt][(wrow + i * 16 + l16) * 32 + psw]);
#pragma unroll
    for (int j = 0; j < 4; ++j)
      bfr[j] = *(const s16x8*)(&Bs[bt][(wcol + j * 16 + l16) * 32 + psw]);
#pragma unroll
    for (int i = 0; i < 4; ++i)
#pragma unroll
      for (int j = 0; j < 4; ++j)
        acc[i][j] = __builtin_amdgcn_mfma_f32_16x16x32_bf16(af[i], bfr[j], acc[i][j], 0, 0, 0);

    if (NT == 2 && kk + 32 == K) {
      epilogue(tileN0);  // n-tile 0 done; its stores cover tile-2's in-flight DMA
#pragma unroll
      for (int i = 0; i < 4; ++i)
#pragma unroll
        for (int j = 0; j < 4; ++j) acc[i][j] = f32x4{0.f, 0.f, 0.f, 0.f};
    }
    bt = bt == 2 ? 0 : bt + 1;
  }
  epilogue(tileN0 + (NT - 1) * 128);
}

// Flash attention. Block = 64 q rows (4 waves x 16 rows). q-rope + scale fused into
// the prologue (rope pairs are in-lane in the A-frag). 64-key tiles staged to LDS
// via global_load_lds, double-buffered, XOR-swizzled slots. One barrier per tile;
// prefetch of t+1 issued right after the barrier. Heavy-first 1D grid (qt descending).
__global__ __launch_bounds__(256, 2) void attn_kernel(
    const u16* __restrict__ q, const u16* __restrict__ k,
    const u16* __restrict__ vT, u16* __restrict__ out) {
  __shared__ __attribute__((aligned(16))) u16 Ks[2][64 * 128];  // [key][slot^], 16KB each
  __shared__ __attribute__((aligned(16))) u16 Vs[2][128 * 64];  // [dim][slot^], 16KB each
  __shared__ __attribute__((aligned(16))) u16 Ps[4][16 * 88];   // per-wave P transpose
  const int tid = threadIdx.x;
  const int w = tid >> 6, lane = tid & 63;
  const int quad = lane >> 4, l16 = lane & 15;
  const int qt = 31 - (blockIdx.x >> 5);  // heavy tiles dispatched first
  const int bh = blockIdx.x & 31;
  const int qbase = qt * 64 + w * 16;

  const u16* qp = q + ((long)bh * 2048 + qbase) * 128;
  const u16* kp = k + (long)bh * 2048 * 128;
  const u16* vp = vT + (long)bh * 128 * 2048;

  // A-frag: Q[m=l16][kdim = c*32 + quad*8 + j], roped + scaled in fp32
  const float spos = (float)(qbase + l16);
  s16x8 qf[4];
#pragma unroll
  for (int c = 0; c < 4; ++c) {
    const s16x8 raw = *(const s16x8*)(qp + l16 * 128 + c * 32 + quad * 8);
    s16x8 ov;
    if (c < 2) {  // dims < 64: rotate pairs (in-lane: 2m, 2m+1)
#pragma unroll
      for (int m = 0; m < 4; ++m) {
        const int jj = c * 16 + quad * 4 + m;
        const float inv = exp2f((float)jj * ROPE_C);
        const float ang = spos * inv;
        const float sn = sinf(ang), cs = cosf(ang);
        const float x0 = bf2f((u16)raw[2 * m]), x1 = bf2f((u16)raw[2 * m + 1]);
        ov[2 * m] = (short)f2bf((x0 * cs - x1 * sn) * QSCALE);
        ov[2 * m + 1] = (short)f2bf((x1 * cs + x0 * sn) * QSCALE);
      }
    } else {      // dims >= 64: pass-through, scale only
#pragma unroll
      for (int e = 0; e < 8; ++e) ov[e] = (short)f2bf(bf2f((u16)raw[e]) * QSCALE);
    }
    qf[c] = ov;
  }

  f32x4 acc[8];
#pragma unroll
  for (int d = 0; d < 8; ++d) acc[d] = f32x4{0.f, 0.f, 0.f, 0.f};
  float mrun[4], lrun[4];
#pragma unroll
  for (int r = 0; r < 4; ++r) { mrun[r] = -1e30f; lrun[r] = 0.f; }

  // stage one 64-key tile into buffer `buf`; wave w: keys [w*16,w*16+16), dims [w*32,w*32+32)
  auto stage = [&](int k0, int buf) {
    const int ko = lane >> 4, cl = lane & 15;
#pragma unroll
    for (int i = 0; i < 4; ++i) {
      const int keyt = w * 16 + i * 4;       // uniform base key of this 1KB chunk
      const int key = keyt + ko;             // this lane's key
      async_copy16(kp + (long)(k0 + key) * 128 + ((cl ^ (key & 15)) << 3),
                   &Ks[buf][keyt * 128]);
    }
    const int ld = lane >> 3, c8 = lane & 7;
#pragma unroll
    for (int i = 0; i < 4; ++i) {
      const int db = w * 32 + i * 8;         // uniform base dim of this 1KB chunk
      const int d = db + ld;
      async_copy16(vp + (long)d * 2048 + k0 + ((c8 ^ (d & 7)) << 3),
                   &Vs[buf][db * 64]);
    }
  };

  stage(0, 0);

  for (int t = 0; t <= qt; ++t) {
    const int k0 = t * 64;
    const u16* Ksc = Ks[t & 1];
    const u16* Vsc = Vs[t & 1];
    __builtin_amdgcn_s_waitcnt(0x0f70);  // vmcnt(0) only: my tile-t DMA done
    __syncthreads();                     // all waves' DMA done; prev buf free
    if (t < qt) stage(k0 + 64, (t + 1) & 1);

    // QK^T: sc[g] over keys k0+g*16+l16
    f32x4 sc[4];
#pragma unroll
    for (int g = 0; g < 4; ++g) {
      sc[g] = f32x4{0.f, 0.f, 0.f, 0.f};
#pragma unroll
      for (int c = 0; c < 4; ++c) {
        const s16x8 kf = *(const s16x8*)(
            &Ksc[(g * 16 + l16) * 128 + ((((c << 2) + quad) ^ l16) << 3)]);
        sc[g] = __builtin_amdgcn_mfma_f32_16x16x32_bf16(qf[c], kf, sc[g], 0, 0, 0);
      }
    }
    if (t == qt) {  // only the diagonal tile needs masking (wave-uniform branch)
#pragma unroll
      for (int g = 0; g < 4; ++g) {
        const int col = k0 + g * 16 + l16;
#pragma unroll
        for (int r = 0; r < 4; ++r)
          if (col > qbase + quad * 4 + r) sc[g][r] = -1e30f;
      }
    }
    // online softmax (exp2 domain)
    float p[4][4], alpha[4];
#pragma unroll
    for (int r = 0; r < 4; ++r) {
      float mx = fmaxf(fmaxf(sc[0][r], sc[1][r]), fmaxf(sc[2][r], sc[3][r]));
#pragma unroll
      for (int off = 1; off < 16; off <<= 1) mx = fmaxf(mx, __shfl_xor(mx, off, 64));
      const float mnew = fmaxf(mrun[r], mx);
      alpha[r] = exp2f(mrun[r] - mnew);
      mrun[r] = mnew;
      float sm = 0.f;
#pragma unroll
      for (int g = 0; g < 4; ++g) { p[g][r] = exp2f(sc[g][r] - mnew); sm += p[g][r]; }
#pragma unroll
      for (int off = 1; off < 16; off <<= 1) sm += __shfl_xor(sm, off, 64);
      lrun[r] = lrun[r] * alpha[r] + sm;
    }
#pragma unroll
    for (int d = 0; d < 8; ++d)
#pragma unroll
      for (int r = 0; r < 4; ++r) acc[d][r] *= alpha[r];
    // P: C-layout -> A-layout via per-wave LDS (stride 88 u16: 16B-aligned rows, bank-spread)
#pragma unroll
    for (int r = 0; r < 4; ++r)
#pragma unroll
      for (int g = 0; g < 4; ++g)
        Ps[w][(quad * 4 + r) * 88 + g * 16 + l16] = f2bf(p[g][r]);
    __builtin_amdgcn_s_waitcnt(0xc07f);  // lgkmcnt(0) only: DS writes visible to my wave
#pragma unroll
    for (int kk = 0; kk < 2; ++kk) {
      const s16x8 pf = *(const s16x8*)(&Ps[w][l16 * 88 + kk * 32 + quad * 8]);
#pragma unroll
      for (int dd = 0; dd < 8; ++dd) {
        const s16x8 vf = *(const s16x8*)(
            &Vsc[(dd * 16 + l16) * 64 + ((((kk << 2) + quad) ^ (l16 & 7)) << 3)]);
        acc[dd] = __builtin_amdgcn_mfma_f32_16x16x32_bf16(pf, vf, acc[dd], 0, 0, 0);
      }
    }
  }

  const int b = bh >> 4, h = bh & 15;
  u16* op = out + ((long)b * 2048 + qbase) * 2048 + h * 128;
#pragma unroll
  for (int d = 0; d < 8; ++d)
#pragma unroll
    for (int r = 0; r < 4; ++r) {
      const float v = acc[d][r] / lrun[r];
      op[(long)(quad * 4 + r) * 2048 + d * 16 + l16] = f2bf(v);
    }
}

extern "C" void kernel_launch(void* const* d_in, const int* in_sizes, int n_in,
                              void* d_out, int out_size, void* d_ws, size_t ws_size,
                              hipStream_t stream) {
  const float* hidden = (const float*)d_in[0];  // [2,2048,2048]
  const float* w_qkv = (const float*)d_in[1];   // [6144,2048]
  const float* w_out = (const float*)d_in[2];   // [2048,2048]
  float* out = (float*)d_out;                   // [2,2048,2048] fp32
  char* ws = (char*)d_ws;

  // workspace layout (112 MB total, all 16B aligned)
  u16* hid_b  = (u16*)(ws + (size_t)0);          // hidden bf16
  u16* wqkv_b = (u16*)(ws + (size_t)16777216);   // w_qkv bf16
  u16* wout_b = (u16*)(ws + (size_t)41943040);   // w_out bf16
  u16* qb     = (u16*)(ws + (size_t)50331648);   // q (unroped) [B,H,S,D]
  u16* kb     = (u16*)(ws + (size_t)67108864);   // k (roped)   [B,H,S,D]
  u16* vb     = (u16*)(ws + (size_t)83886080);   // v^T [B,H,D,S]
  u16* ao     = (u16*)(ws + (size_t)100663296);  // attn out [B,S,E]

  cast3_kernel<<<24576, 256, 0, stream>>>(hidden, hid_b, 2097152,
                                          w_qkv, wqkv_b, 3145728,
                                          w_out, wout_b, 1048576);

  // qkv projection, 2 n-tiles/block, fused split/transpose/k-rope epilogue
  gemm_bt_kernel<1, 2><<<dim3(24, 32), 256, 0, stream>>>(hid_b, wqkv_b, 2048, 6144,
                                                         nullptr, qb, kb, vb);
  // causal flash attention (q-rope + scale in prologue)
  attn_kernel<<<1024, 256, 0, stream>>>(qb, kb, vb, ao);
  // output projection -> fp32
  gemm_bt_kernel<0, 1><<<dim3(16, 32), 256, 0, stream>>>(ao, wout_b, 2048, 2048,
                                                         out, nullptr, nullptr, nullptr);
}

// Round 6
// 527.011 us; speedup vs baseline: 4.2452x; 4.2452x over previous
//
#include <hip/hip_runtime.h>

typedef unsigned short u16;
typedef unsigned int u32;
typedef __attribute__((ext_vector_type(4))) float f32x4;
typedef __attribute__((ext_vector_type(8))) short s16x8;

#define DEVI static __device__ __forceinline__

// B=2, S=2048, E=2048, H=16, D=128, MP=4, local=512; qkv cols: [q(512) v(512) k(512)] x4
// k-rope fused into QKV-GEMM epilogue; q-rope (+ (1/sqrt(128))*log2(e) scale) fused into
// attention prologue; softmax in exp2 domain.

#define ROPE_C (-13.287712379549449f / 32.0f)  // -log2(10000)/32
#define QSCALE 0.12751743f                     // log2(e)/sqrt(128)

DEVI u16 f2bf(float f) {
  u32 u = __float_as_uint(f);
  return (u16)((u + 0x7FFFu + ((u >> 16) & 1u)) >> 16);  // round-to-nearest-even
}
DEVI float bf2f(u16 h) { return __uint_as_float(((u32)h) << 16); }

DEVI void async_copy16(const u16* g, u16* l) {
  // dest = wave-uniform LDS base + lane*16 (gfx950 global_load_lds_dwordx4)
  __builtin_amdgcn_global_load_lds((__attribute__((address_space(1))) void*)g,
                                   (__attribute__((address_space(3))) void*)l, 16, 0, 0);
}

// fused fp32->bf16 cast of all three inputs
__global__ __launch_bounds__(256) void cast3_kernel(
    const float* __restrict__ s0, u16* __restrict__ d0, int n0,
    const float* __restrict__ s1, u16* __restrict__ d1, int n1,
    const float* __restrict__ s2, u16* __restrict__ d2, int n2) {
  int i = blockIdx.x * 256 + threadIdx.x;
  const float* s;
  u16* d;
  if (i < n0) {
    s = s0; d = d0;
  } else if (i < n0 + n1) {
    s = s1; d = d1; i -= n0;
  } else if (i < n0 + n1 + n2) {
    s = s2; d = d2; i -= n0 + n1;
  } else {
    return;
  }
  const float4 v = ((const float4*)s)[i];
  ushort4 o;
  o.x = f2bf(v.x); o.y = f2bf(v.y); o.z = f2bf(v.z); o.w = f2bf(v.w);
  ((ushort4*)d)[i] = o;
}

// C[m,n] = sum_k A[m,k]*B[n,k]; A,B row-major bf16, K contiguous (B^T GEMM).
// 128x128 tile, BK=32, 4 waves 2x2 of 64x64, 16x16x32 MFMA, 4x4 frags/wave.
// A staged through LDS (3-deep, global_load_lds w16, XOR-swizzled, raw s_barrier).
// B loaded DIRECT global->VGPR (L2/L3-resident weights; halves LDS traffic), 1-iter
// register prefetch. Issue order/iter: [copy bnxt->bcur][loadB t+1][stageA t+2];
// top-of-loop vmcnt(2) leaves only A(t+2) in flight (FIFO => B(t), A(t) landed).
// EPI=0: C fp32 store. EPI=1: scatter qkv -> q[B,H,S,D], k(roped)[B,H,S,D], v^T[B,H,D,S].
template <int EPI>
__global__ __launch_bounds__(256, 3) void gemm_bt_kernel(
    const u16* __restrict__ A, const u16* __restrict__ Bm, int K, int N,
    float* __restrict__ C, u16* __restrict__ qo, u16* __restrict__ ko, u16* __restrict__ vo) {
  __shared__ __attribute__((aligned(16))) u16 As[3][128 * 32];  // 8KB each
  const int tid = threadIdx.x;
  const int w = tid >> 6, lane = tid & 63;
  const int quad = lane >> 4, l16 = lane & 15;
  const int wrow = (w >> 1) * 64, wcol = (w & 1) * 64;
  const long tileM = (long)blockIdx.y * 128;
  const long tileN = (long)blockIdx.x * 128;

  f32x4 acc[4][4];
#pragma unroll
  for (int i = 0; i < 4; ++i)
#pragma unroll
    for (int j = 0; j < 4; ++j) acc[i][j] = f32x4{0.f, 0.f, 0.f, 0.f};

  // A staging: wave w covers tile rows [w*32, w*32+32) in two 16-row chunks.
  // lane -> row r0+(lane>>2), LDS chunk pos p=lane&3; global col chunk = p ^ ((row>>1)&3).
  const u16* aptr[2];
  int ldso[2];
#pragma unroll
  for (int c = 0; c < 2; ++c) {
    const int r0 = (w * 2 + c) * 16;
    const int row = r0 + (lane >> 2);
    const int colsw = (((lane & 3) ^ ((row >> 1) & 3)) << 3);
    aptr[c] = A + (tileM + row) * (long)K + colsw;
    ldso[c] = r0 * 32;
  }
  auto stageA = [&](int k0, int buf) {
#pragma unroll
    for (int c = 0; c < 2; ++c) async_copy16(aptr[c] + k0, &As[buf][ldso[c]]);
  };

  // B direct: frag j lane address = row (wcol+j*16+l16), k-chunk quad*8
  const u16* bbase[4];
#pragma unroll
  for (int j = 0; j < 4; ++j)
    bbase[j] = Bm + (tileN + wcol + j * 16 + l16) * (long)K + quad * 8;

  s16x8 bcur[4], bnxt[4];

  // prologue issue order: A(0) x2, B(0) x4, A(32) x2
  stageA(0, 0);
#pragma unroll
  for (int j = 0; j < 4; ++j) bnxt[j] = *(const s16x8*)(bbase[j]);
  stageA(32, 1);

  // read-side swizzled chunk position for A (lane-constant)
  const int psw = (quad ^ ((l16 >> 1) & 3)) << 3;

  int bt = 0;
  for (int k0 = 0; k0 < K; k0 += 32) {
    if (k0 + 32 < K)
      __builtin_amdgcn_s_waitcnt(0x0f72);  // vmcnt(2): only A(t+1)'s 2 DMAs may remain
    else
      __builtin_amdgcn_s_waitcnt(0x0f70);  // last iter: vmcnt(0)
    __builtin_amdgcn_s_barrier();          // raw barrier: A(t) visible to all waves
#pragma unroll
    for (int j = 0; j < 4; ++j) bcur[j] = bnxt[j];  // free: vmcnt above covered B(t)
    if (k0 + 32 < K)
#pragma unroll
      for (int j = 0; j < 4; ++j) bnxt[j] = *(const s16x8*)(bbase[j] + k0 + 32);
    if (k0 + 64 < K) stageA(k0 + 64, bt == 0 ? 2 : bt - 1);

    s16x8 af[4];
#pragma unroll
    for (int i = 0; i < 4; ++i)
      af[i] = *(const s16x8*)(&As[bt][(wrow + i * 16 + l16) * 32 + psw]);
#pragma unroll
    for (int i = 0; i < 4; ++i)
#pragma unroll
      for (int j = 0; j < 4; ++j)
        acc[i][j] = __builtin_amdgcn_mfma_f32_16x16x32_bf16(af[i], bcur[j], acc[i][j], 0, 0, 0);
    bt = bt == 2 ? 0 : bt + 1;
  }

  // ---- inline epilogue (single call site; keeps acc in registers) ----
  const int b = (int)(tileM >> 11);  // 128-row tile never straddles batch (2048%128==0)
#pragma unroll
  for (int i = 0; i < 4; ++i) {
#pragma unroll
    for (int j = 0; j < 4; ++j) {
      const int rowb = (int)((tileM + wrow + i * 16 + quad * 4) & 2047);  // s of reg 0
      if (EPI == 0) {
#pragma unroll
        for (int r = 0; r < 4; ++r) {
          const long row = tileM + wrow + i * 16 + quad * 4 + r;
          C[row * N + tileN + wcol + j * 16 + l16] = acc[i][j][r];
        }
      } else {
        const long col0 = tileN + wcol + j * 16;  // wave-uniform base col of this frag
        const int mp = (int)(col0 / 1536);
        const int cc0 = (int)(col0 - (long)mp * 1536);
        const int part = cc0 >> 9;     // 0:q 1:v 2:k (uniform: 16-col group in one chunk)
        const int idx0 = cc0 & 511;
        const int head = mp * 4 + (idx0 >> 7);
        const int dim0 = idx0 & 127;   // base dim; lane dim = dim0 + l16
        const int dim = dim0 + l16;
        const long bh = (long)(b * 16 + head);
        if (part == 1) {
          // v stored transposed [B,H,D,S]
#pragma unroll
          for (int r = 0; r < 4; ++r)
            vo[(bh * 128 + dim) * 2048 + rowb + r] = f2bf(acc[i][j][r]);
        } else {
          float y[4];
          if (part == 2 && dim0 < 64) {
            // k-rope: pair partner is adjacent lane (col parity == l16 parity)
            const int jj = dim >> 1;  // same for both lanes of the pair
            const float inv = exp2f((float)jj * ROPE_C);
#pragma unroll
            for (int r = 0; r < 4; ++r) {
              const float v = acc[i][j][r];
              const float pv = __shfl_xor(v, 1, 64);
              const float ang = (float)(rowb + r) * inv;
              const float sn = sinf(ang), cs = cosf(ang);
              y[r] = (l16 & 1) ? (v * cs + pv * sn) : (v * cs - pv * sn);
            }
          } else {
#pragma unroll
            for (int r = 0; r < 4; ++r) y[r] = acc[i][j][r];
          }
          u16* dst = (part == 0) ? qo : ko;
#pragma unroll
          for (int r = 0; r < 4; ++r)
            dst[(bh * 2048 + rowb + r) * 128 + dim] = f2bf(y[r]);
        }
      }
    }
  }
}

// Flash attention. Block = 64 q rows (4 waves x 16 rows). q-rope + scale fused into
// the prologue (rope pairs are in-lane in the A-frag). 64-key tiles staged to LDS
// via global_load_lds, double-buffered, XOR-swizzled slots. One barrier per tile;
// prefetch of t+1 issued right after the barrier. Heavy-first 1D grid (qt descending).
__global__ __launch_bounds__(256, 2) void attn_kernel(
    const u16* __restrict__ q, const u16* __restrict__ k,
    const u16* __restrict__ vT, u16* __restrict__ out) {
  __shared__ __attribute__((aligned(16))) u16 Ks[2][64 * 128];  // [key][slot^], 16KB each
  __shared__ __attribute__((aligned(16))) u16 Vs[2][128 * 64];  // [dim][slot^], 16KB each
  __shared__ __attribute__((aligned(16))) u16 Ps[4][16 * 88];   // per-wave P transpose
  const int tid = threadIdx.x;
  const int w = tid >> 6, lane = tid & 63;
  const int quad = lane >> 4, l16 = lane & 15;
  const int qt = 31 - (blockIdx.x >> 5);  // heavy tiles dispatched first
  const int bh = blockIdx.x & 31;
  const int qbase = qt * 64 + w * 16;

  const u16* qp = q + ((long)bh * 2048 + qbase) * 128;
  const u16* kp = k + (long)bh * 2048 * 128;
  const u16* vp = vT + (long)bh * 128 * 2048;

  // A-frag: Q[m=l16][kdim = c*32 + quad*8 + j], roped + scaled in fp32
  const float spos = (float)(qbase + l16);
  s16x8 qf[4];
#pragma unroll
  for (int c = 0; c < 4; ++c) {
    const s16x8 raw = *(const s16x8*)(qp + l16 * 128 + c * 32 + quad * 8);
    s16x8 ov;
    if (c < 2) {  // dims < 64: rotate pairs (in-lane: 2m, 2m+1)
#pragma unroll
      for (int m = 0; m < 4; ++m) {
        const int jj = c * 16 + quad * 4 + m;
        const float inv = exp2f((float)jj * ROPE_C);
        const float ang = spos * inv;
        const float sn = sinf(ang), cs = cosf(ang);
        const float x0 = bf2f((u16)raw[2 * m]), x1 = bf2f((u16)raw[2 * m + 1]);
        ov[2 * m] = (short)f2bf((x0 * cs - x1 * sn) * QSCALE);
        ov[2 * m + 1] = (short)f2bf((x1 * cs + x0 * sn) * QSCALE);
      }
    } else {      // dims >= 64: pass-through, scale only
#pragma unroll
      for (int e = 0; e < 8; ++e) ov[e] = (short)f2bf(bf2f((u16)raw[e]) * QSCALE);
    }
    qf[c] = ov;
  }

  f32x4 acc[8];
#pragma unroll
  for (int d = 0; d < 8; ++d) acc[d] = f32x4{0.f, 0.f, 0.f, 0.f};
  float mrun[4], lrun[4];
#pragma unroll
  for (int r = 0; r < 4; ++r) { mrun[r] = -1e30f; lrun[r] = 0.f; }

  // stage one 64-key tile into buffer `buf`; wave w: keys [w*16,w*16+16), dims [w*32,w*32+32)
  auto stage = [&](int k0, int buf) {
    const int ko = lane >> 4, cl = lane & 15;
#pragma unroll
    for (int i = 0; i < 4; ++i) {
      const int keyt = w * 16 + i * 4;       // uniform base key of this 1KB chunk
      const int key = keyt + ko;             // this lane's key
      async_copy16(kp + (long)(k0 + key) * 128 + ((cl ^ (key & 15)) << 3),
                   &Ks[buf][keyt * 128]);
    }
    const int ld = lane >> 3, c8 = lane & 7;
#pragma unroll
    for (int i = 0; i < 4; ++i) {
      const int db = w * 32 + i * 8;         // uniform base dim of this 1KB chunk
      const int d = db + ld;
      async_copy16(vp + (long)d * 2048 + k0 + ((c8 ^ (d & 7)) << 3),
                   &Vs[buf][db * 64]);
    }
  };

  stage(0, 0);

  for (int t = 0; t <= qt; ++t) {
    const int k0 = t * 64;
    const u16* Ksc = Ks[t & 1];
    const u16* Vsc = Vs[t & 1];
    __builtin_amdgcn_s_waitcnt(0x0f70);  // vmcnt(0) only: my tile-t DMA done
    __syncthreads();                     // all waves' DMA done; prev buf free
    if (t < qt) stage(k0 + 64, (t + 1) & 1);

    // QK^T: sc[g] over keys k0+g*16+l16
    f32x4 sc[4];
#pragma unroll
    for (int g = 0; g < 4; ++g) {
      sc[g] = f32x4{0.f, 0.f, 0.f, 0.f};
#pragma unroll
      for (int c = 0; c < 4; ++c) {
        const s16x8 kf = *(const s16x8*)(
            &Ksc[(g * 16 + l16) * 128 + ((((c << 2) + quad) ^ l16) << 3)]);
        sc[g] = __builtin_amdgcn_mfma_f32_16x16x32_bf16(qf[c], kf, sc[g], 0, 0, 0);
      }
    }
    if (t == qt) {  // only the diagonal tile needs masking (wave-uniform branch)
#pragma unroll
      for (int g = 0; g < 4; ++g) {
        const int col = k0 + g * 16 + l16;
#pragma unroll
        for (int r = 0; r < 4; ++r)
          if (col > qbase + quad * 4 + r) sc[g][r] = -1e30f;
      }
    }
    // online softmax (exp2 domain)
    float p[4][4], alpha[4];
#pragma unroll
    for (int r = 0; r < 4; ++r) {
      float mx = fmaxf(fmaxf(sc[0][r], sc[1][r]), fmaxf(sc[2][r], sc[3][r]));
#pragma unroll
      for (int off = 1; off < 16; off <<= 1) mx = fmaxf(mx, __shfl_xor(mx, off, 64));
      const float mnew = fmaxf(mrun[r], mx);
      alpha[r] = exp2f(mrun[r] - mnew);
      mrun[r] = mnew;
      float sm = 0.f;
#pragma unroll
      for (int g = 0; g < 4; ++g) { p[g][r] = exp2f(sc[g][r] - mnew); sm += p[g][r]; }
#pragma unroll
      for (int off = 1; off < 16; off <<= 1) sm += __shfl_xor(sm, off, 64);
      lrun[r] = lrun[r] * alpha[r] + sm;
    }
#pragma unroll
    for (int d = 0; d < 8; ++d)
#pragma unroll
      for (int r = 0; r < 4; ++r) acc[d][r] *= alpha[r];
    // P: C-layout -> A-layout via per-wave LDS (stride 88 u16: 16B-aligned rows, bank-spread)
#pragma unroll
    for (int r = 0; r < 4; ++r)
#pragma unroll
      for (int g = 0; g < 4; ++g)
        Ps[w][(quad * 4 + r) * 88 + g * 16 + l16] = f2bf(p[g][r]);
    __builtin_amdgcn_s_waitcnt(0xc07f);  // lgkmcnt(0) only: DS writes visible to my wave
#pragma unroll
    for (int kk = 0; kk < 2; ++kk) {
      const s16x8 pf = *(const s16x8*)(&Ps[w][l16 * 88 + kk * 32 + quad * 8]);
#pragma unroll
      for (int dd = 0; dd < 8; ++dd) {
        const s16x8 vf = *(const s16x8*)(
            &Vsc[(dd * 16 + l16) * 64 + ((((kk << 2) + quad) ^ (l16 & 7)) << 3)]);
        acc[dd] = __builtin_amdgcn_mfma_f32_16x16x32_bf16(pf, vf, acc[dd], 0, 0, 0);
      }
    }
  }

  const int b = bh >> 4, h = bh & 15;
  u16* op = out + ((long)b * 2048 + qbase) * 2048 + h * 128;
#pragma unroll
  for (int d = 0; d < 8; ++d)
#pragma unroll
    for (int r = 0; r < 4; ++r) {
      const float v = acc[d][r] / lrun[r];
      op[(long)(quad * 4 + r) * 2048 + d * 16 + l16] = f2bf(v);
    }
}

extern "C" void kernel_launch(void* const* d_in, const int* in_sizes, int n_in,
                              void* d_out, int out_size, void* d_ws, size_t ws_size,
                              hipStream_t stream) {
  const float* hidden = (const float*)d_in[0];  // [2,2048,2048]
  const float* w_qkv = (const float*)d_in[1];   // [6144,2048]
  const float* w_out = (const float*)d_in[2];   // [2048,2048]
  float* out = (float*)d_out;                   // [2,2048,2048] fp32
  char* ws = (char*)d_ws;

  // workspace layout (112 MB total, all 16B aligned)
  u16* hid_b  = (u16*)(ws + (size_t)0);          // hidden bf16
  u16* wqkv_b = (u16*)(ws + (size_t)16777216);   // w_qkv bf16
  u16* wout_b = (u16*)(ws + (size_t)41943040);   // w_out bf16
  u16* qb     = (u16*)(ws + (size_t)50331648);   // q (unroped) [B,H,S,D]
  u16* kb     = (u16*)(ws + (size_t)67108864);   // k (roped)   [B,H,S,D]
  u16* vb     = (u16*)(ws + (size_t)83886080);   // v^T [B,H,D,S]
  u16* ao     = (u16*)(ws + (size_t)100663296);  // attn out [B,S,E]

  cast3_kernel<<<24576, 256, 0, stream>>>(hidden, hid_b, 2097152,
                                          w_qkv, wqkv_b, 3145728,
                                          w_out, wout_b, 1048576);

  // qkv projection, fused split/transpose/k-rope epilogue
  gemm_bt_kernel<1><<<dim3(48, 32), 256, 0, stream>>>(hid_b, wqkv_b, 2048, 6144,
                                                      nullptr, qb, kb, vb);
  // causal flash attention (q-rope + scale in prologue)
  attn_kernel<<<1024, 256, 0, stream>>>(qb, kb, vb, ao);
  // output projection -> fp32
  gemm_bt_kernel<0><<<dim3(16, 32), 256, 0, stream>>>(ao, wout_b, 2048, 2048,
                                                      out, nullptr, nullptr, nullptr);
}

// Round 7
// 461.425 us; speedup vs baseline: 4.8486x; 1.1421x over previous
//
#include <hip/hip_runtime.h>

typedef unsigned short u16;
typedef unsigned int u32;
typedef __attribute__((ext_vector_type(4))) float f32x4;
typedef __attribute__((ext_vector_type(8))) short s16x8;

#define DEVI static __device__ __forceinline__

// B=2, S=2048, E=2048, H=16, D=128, MP=4, local=512; qkv cols: [q(512) v(512) k(512)] x4
// k-rope fused into QKV-GEMM epilogue; q-rope (+ (1/sqrt(128))*log2(e) scale) fused into
// attention prologue; softmax in exp2 domain.

#define ROPE_C (-13.287712379549449f / 32.0f)  // -log2(10000)/32
#define QSCALE 0.12751743f                     // log2(e)/sqrt(128)

DEVI u16 f2bf(float f) {
  u32 u = __float_as_uint(f);
  return (u16)((u + 0x7FFFu + ((u >> 16) & 1u)) >> 16);  // round-to-nearest-even
}
DEVI float bf2f(u16 h) { return __uint_as_float(((u32)h) << 16); }

DEVI void async_copy16(const u16* g, u16* l) {
  // dest = wave-uniform LDS base + lane*16 (gfx950 global_load_lds_dwordx4)
  __builtin_amdgcn_global_load_lds((__attribute__((address_space(1))) void*)g,
                                   (__attribute__((address_space(3))) void*)l, 16, 0, 0);
}

// fused fp32->bf16 cast of all three inputs
__global__ __launch_bounds__(256) void cast3_kernel(
    const float* __restrict__ s0, u16* __restrict__ d0, int n0,
    const float* __restrict__ s1, u16* __restrict__ d1, int n1,
    const float* __restrict__ s2, u16* __restrict__ d2, int n2) {
  int i = blockIdx.x * 256 + threadIdx.x;
  const float* s;
  u16* d;
  if (i < n0) {
    s = s0; d = d0;
  } else if (i < n0 + n1) {
    s = s1; d = d1; i -= n0;
  } else if (i < n0 + n1 + n2) {
    s = s2; d = d2; i -= n0 + n1;
  } else {
    return;
  }
  const float4 v = ((const float4*)s)[i];
  ushort4 o;
  o.x = f2bf(v.x); o.y = f2bf(v.y); o.z = f2bf(v.z); o.w = f2bf(v.w);
  ((ushort4*)d)[i] = o;
}

// C[m,n] = sum_k A[m,k]*B[n,k]; A,B row-major bf16, K contiguous (B^T GEMM).
// 128x128 tile, BK=32, 4 waves 2x2 of 64x64, 16x16x32 MFMA, 4x4 frags/wave.
// R4 structure (best measured): A,B staged through 3-deep LDS via global_load_lds w16,
// XOR-swizzled, vmcnt(4) + raw s_barrier in steady state (tile t+1's DMA stays in
// flight across the barrier). Single-call-site inline epilogue (acc stays in regs).
// EPI=0: C fp32 store. EPI=1: scatter qkv -> q[B,H,S,D], k(roped)[B,H,S,D], v^T[B,H,D,S].
template <int EPI>
__global__ __launch_bounds__(256, 3) void gemm_bt_kernel(
    const u16* __restrict__ A, const u16* __restrict__ Bm, int K, int N,
    float* __restrict__ C, u16* __restrict__ qo, u16* __restrict__ ko, u16* __restrict__ vo) {
  __shared__ __attribute__((aligned(16))) u16 As[3][128 * 32];  // 8KB each
  __shared__ __attribute__((aligned(16))) u16 Bs[3][128 * 32];  // 8KB each
  const int tid = threadIdx.x;
  const int w = tid >> 6, lane = tid & 63;
  const int quad = lane >> 4, l16 = lane & 15;
  const int wrow = (w >> 1) * 64, wcol = (w & 1) * 64;
  const long tileM = (long)blockIdx.y * 128;
  const long tileN = (long)blockIdx.x * 128;

  f32x4 acc[4][4];
#pragma unroll
  for (int i = 0; i < 4; ++i)
#pragma unroll
    for (int j = 0; j < 4; ++j) acc[i][j] = f32x4{0.f, 0.f, 0.f, 0.f};

  // staging: wave w covers tile rows [w*32, w*32+32) in two 16-row chunks.
  // lane -> row r0+(lane>>2), LDS chunk pos p=lane&3; global col chunk = p ^ ((row>>1)&3).
  const u16* aptr[2];
  const u16* bptr[2];
  int ldso[2];
#pragma unroll
  for (int c = 0; c < 2; ++c) {
    const int r0 = (w * 2 + c) * 16;
    const int row = r0 + (lane >> 2);
    const int colsw = (((lane & 3) ^ ((row >> 1) & 3)) << 3);
    aptr[c] = A + (tileM + row) * (long)K + colsw;
    bptr[c] = Bm + (tileN + row) * (long)K + colsw;
    ldso[c] = r0 * 32;
  }

  auto stage = [&](int k0, int buf) {
    // 4 DMAs per wave per tile (2 A + 2 B) -> vmcnt granularity of 4
#pragma unroll
    for (int c = 0; c < 2; ++c) {
      async_copy16(aptr[c] + k0, &As[buf][ldso[c]]);
      async_copy16(bptr[c] + k0, &Bs[buf][ldso[c]]);
    }
  };

  stage(0, 0);
  stage(32, 1);

  // read-side swizzled chunk position (lane-constant)
  const int psw = (quad ^ ((l16 >> 1) & 3)) << 3;

  int bt = 0;
  for (int k0 = 0; k0 < K; k0 += 32) {
    if (k0 + 32 < K)
      __builtin_amdgcn_s_waitcnt(0x0f74);  // vmcnt(4): tile t landed, t+1 in flight
    else
      __builtin_amdgcn_s_waitcnt(0x0f70);  // last tile: vmcnt(0)
    __builtin_amdgcn_s_barrier();          // raw barrier: no compiler-forced drain
    if (k0 + 64 < K) stage(k0 + 64, bt == 0 ? 2 : bt - 1);  // overwrite t-1's buffer

    s16x8 af[4], bfr[4];
#pragma unroll
    for (int i = 0; i < 4; ++i)
      af[i] = *(const s16x8*)(&As[bt][(wrow + i * 16 + l16) * 32 + psw]);
#pragma unroll
    for (int j = 0; j < 4; ++j)
      bfr[j] = *(const s16x8*)(&Bs[bt][(wcol + j * 16 + l16) * 32 + psw]);
#pragma unroll
    for (int i = 0; i < 4; ++i)
#pragma unroll
      for (int j = 0; j < 4; ++j)
        acc[i][j] = __builtin_amdgcn_mfma_f32_16x16x32_bf16(af[i], bfr[j], acc[i][j], 0, 0, 0);
    bt = bt == 2 ? 0 : bt + 1;
  }

  // ---- inline epilogue (single call site; keeps acc in registers) ----
  const int b = (int)(tileM >> 11);  // 128-row tile never straddles batch (2048%128==0)
#pragma unroll
  for (int i = 0; i < 4; ++i) {
#pragma unroll
    for (int j = 0; j < 4; ++j) {
      const int rowb = (int)((tileM + wrow + i * 16 + quad * 4) & 2047);  // s of reg 0
      if (EPI == 0) {
#pragma unroll
        for (int r = 0; r < 4; ++r) {
          const long row = tileM + wrow + i * 16 + quad * 4 + r;
          C[row * N + tileN + wcol + j * 16 + l16] = acc[i][j][r];
        }
      } else {
        const long col0 = tileN + wcol + j * 16;  // wave-uniform base col of this frag
        const int mp = (int)(col0 / 1536);
        const int cc0 = (int)(col0 - (long)mp * 1536);
        const int part = cc0 >> 9;     // 0:q 1:v 2:k (uniform: 16-col group in one chunk)
        const int idx0 = cc0 & 511;
        const int head = mp * 4 + (idx0 >> 7);
        const int dim0 = idx0 & 127;   // base dim; lane dim = dim0 + l16
        const int dim = dim0 + l16;
        const long bh = (long)(b * 16 + head);
        if (part == 1) {
          // v stored transposed [B,H,D,S]
#pragma unroll
          for (int r = 0; r < 4; ++r)
            vo[(bh * 128 + dim) * 2048 + rowb + r] = f2bf(acc[i][j][r]);
        } else {
          float y[4];
          if (part == 2 && dim0 < 64) {
            // k-rope: pair partner is adjacent lane (col parity == l16 parity)
            const int jj = dim >> 1;  // same for both lanes of the pair
            const float inv = exp2f((float)jj * ROPE_C);
#pragma unroll
            for (int r = 0; r < 4; ++r) {
              const float v = acc[i][j][r];
              const float pv = __shfl_xor(v, 1, 64);
              const float ang = (float)(rowb + r) * inv;
              const float sn = sinf(ang), cs = cosf(ang);
              y[r] = (l16 & 1) ? (v * cs + pv * sn) : (v * cs - pv * sn);
            }
          } else {
#pragma unroll
            for (int r = 0; r < 4; ++r) y[r] = acc[i][j][r];
          }
          u16* dst = (part == 0) ? qo : ko;
#pragma unroll
          for (int r = 0; r < 4; ++r)
            dst[(bh * 2048 + rowb + r) * 128 + dim] = f2bf(y[r]);
        }
      }
    }
  }
}

// Flash attention v3. Block = 64 q rows (4 waves x 16 rows); 32-key tiles (halved from
// 64) -> LDS 37KB -> 4 blocks/CU = 16 waves/CU (was 8): halves the per-barrier serial
// chain and doubles latency-hiding waves. K/V staged via global_load_lds, double-
// buffered, XOR-swizzled. q-rope + scale fused in prologue. Heavy-first 1D grid.
__global__ __launch_bounds__(256, 4) void attn_kernel(
    const u16* __restrict__ q, const u16* __restrict__ k,
    const u16* __restrict__ vT, u16* __restrict__ out) {
  __shared__ __attribute__((aligned(16))) u16 Ks[2][32 * 128];  // 8KB each
  __shared__ __attribute__((aligned(16))) u16 Vs[2][128 * 32];  // 8KB each
  __shared__ __attribute__((aligned(16))) u16 Ps[4][16 * 40];   // per-wave P transpose
  const int tid = threadIdx.x;
  const int w = tid >> 6, lane = tid & 63;
  const int quad = lane >> 4, l16 = lane & 15;
  const int qt = 31 - (blockIdx.x >> 5);  // heavy tiles dispatched first
  const int bh = blockIdx.x & 31;
  const int qbase = qt * 64 + w * 16;

  const u16* qp = q + ((long)bh * 2048 + qbase) * 128;
  const u16* kp = k + (long)bh * 2048 * 128;
  const u16* vp = vT + (long)bh * 128 * 2048;

  // A-frag: Q[m=l16][kdim = c*32 + quad*8 + j], roped + scaled in fp32
  const float spos = (float)(qbase + l16);
  s16x8 qf[4];
#pragma unroll
  for (int c = 0; c < 4; ++c) {
    const s16x8 raw = *(const s16x8*)(qp + l16 * 128 + c * 32 + quad * 8);
    s16x8 ov;
    if (c < 2) {  // dims < 64: rotate pairs (in-lane: 2m, 2m+1)
#pragma unroll
      for (int m = 0; m < 4; ++m) {
        const int jj = c * 16 + quad * 4 + m;
        const float inv = exp2f((float)jj * ROPE_C);
        const float ang = spos * inv;
        const float sn = sinf(ang), cs = cosf(ang);
        const float x0 = bf2f((u16)raw[2 * m]), x1 = bf2f((u16)raw[2 * m + 1]);
        ov[2 * m] = (short)f2bf((x0 * cs - x1 * sn) * QSCALE);
        ov[2 * m + 1] = (short)f2bf((x1 * cs + x0 * sn) * QSCALE);
      }
    } else {      // dims >= 64: pass-through, scale only
#pragma unroll
      for (int e = 0; e < 8; ++e) ov[e] = (short)f2bf(bf2f((u16)raw[e]) * QSCALE);
    }
    qf[c] = ov;
  }

  f32x4 acc[8];
#pragma unroll
  for (int d = 0; d < 8; ++d) acc[d] = f32x4{0.f, 0.f, 0.f, 0.f};
  float mrun[4], lrun[4];
#pragma unroll
  for (int r = 0; r < 4; ++r) { mrun[r] = -1e30f; lrun[r] = 0.f; }

  // stage one 32-key tile: wave w stages keys [w*8,w*8+8) and dims [w*32,w*32+32)
  auto stage = [&](int k0, int buf) {
    const int ko = lane >> 4, cl = lane & 15;
#pragma unroll
    for (int i = 0; i < 2; ++i) {
      const int keyt = w * 8 + i * 4;        // uniform base key of this 1KB chunk
      const int key = keyt + ko;             // this lane's key (0..31)
      async_copy16(kp + (long)(k0 + key) * 128 + ((cl ^ (key & 15)) << 3),
                   &Ks[buf][keyt * 128]);
    }
    const int ld = lane >> 2, c4 = lane & 3;
#pragma unroll
    for (int i = 0; i < 2; ++i) {
      const int db = w * 32 + i * 16;        // uniform base dim of this 1KB chunk
      const int d = db + ld;
      async_copy16(vp + (long)d * 2048 + k0 + ((c4 ^ ((d >> 1) & 3)) << 3),
                   &Vs[buf][db * 32]);
    }
  };

  stage(0, 0);

  const int nt = 2 * qt + 2;  // block covers keys up to (qt*64+63); 32-key tiles
  for (int t = 0; t < nt; ++t) {
    const int k0 = t * 32;
    const u16* Ksc = Ks[t & 1];
    const u16* Vsc = Vs[t & 1];
    __builtin_amdgcn_s_waitcnt(0x0f70);  // vmcnt(0) only: my tile-t DMA done
    __syncthreads();                     // all waves' DMA done; prev buf free
    if (t + 1 < nt) stage(k0 + 32, (t + 1) & 1);

    // QK^T: sc[g] over keys k0+g*16+l16
    f32x4 sc[2];
#pragma unroll
    for (int g = 0; g < 2; ++g) {
      sc[g] = f32x4{0.f, 0.f, 0.f, 0.f};
#pragma unroll
      for (int c = 0; c < 4; ++c) {
        const s16x8 kf = *(const s16x8*)(
            &Ksc[(g * 16 + l16) * 128 + ((((c << 2) + quad) ^ l16) << 3)]);
        sc[g] = __builtin_amdgcn_mfma_f32_16x16x32_bf16(qf[c], kf, sc[g], 0, 0, 0);
      }
    }
    if (k0 + 31 > qbase) {  // tile may cross the diagonal for this wave (uniform branch)
#pragma unroll
      for (int g = 0; g < 2; ++g) {
        const int col = k0 + g * 16 + l16;
#pragma unroll
        for (int r = 0; r < 4; ++r)
          if (col > qbase + quad * 4 + r) sc[g][r] = -1e30f;
      }
    }
    // online softmax (exp2 domain)
    float p[2][4], alpha[4];
#pragma unroll
    for (int r = 0; r < 4; ++r) {
      float mx = fmaxf(sc[0][r], sc[1][r]);
#pragma unroll
      for (int off = 1; off < 16; off <<= 1) mx = fmaxf(mx, __shfl_xor(mx, off, 64));
      const float mnew = fmaxf(mrun[r], mx);
      alpha[r] = exp2f(mrun[r] - mnew);
      mrun[r] = mnew;
      float sm = 0.f;
#pragma unroll
      for (int g = 0; g < 2; ++g) { p[g][r] = exp2f(sc[g][r] - mnew); sm += p[g][r]; }
#pragma unroll
      for (int off = 1; off < 16; off <<= 1) sm += __shfl_xor(sm, off, 64);
      lrun[r] = lrun[r] * alpha[r] + sm;
    }
#pragma unroll
    for (int d = 0; d < 8; ++d)
#pragma unroll
      for (int r = 0; r < 4; ++r) acc[d][r] *= alpha[r];
    // P: C-layout -> A-layout via per-wave LDS (stride 40 u16: 16B-aligned rows, 2-way free)
#pragma unroll
    for (int r = 0; r < 4; ++r)
#pragma unroll
      for (int g = 0; g < 2; ++g)
        Ps[w][(quad * 4 + r) * 40 + g * 16 + l16] = f2bf(p[g][r]);
    __builtin_amdgcn_s_waitcnt(0xc07f);  // lgkmcnt(0) only: DS writes visible to my wave
    const s16x8 pf = *(const s16x8*)(&Ps[w][l16 * 40 + quad * 8]);
#pragma unroll
    for (int dd = 0; dd < 8; ++dd) {  // B-frag: V^T[n=dim][key = quad*8+j]
      const s16x8 vf = *(const s16x8*)(
          &Vsc[(dd * 16 + l16) * 32 + ((quad ^ ((l16 >> 1) & 3)) << 3)]);
      acc[dd] = __builtin_amdgcn_mfma_f32_16x16x32_bf16(pf, vf, acc[dd], 0, 0, 0);
    }
  }

  const int b = bh >> 4, h = bh & 15;
  u16* op = out + ((long)b * 2048 + qbase) * 2048 + h * 128;
#pragma unroll
  for (int d = 0; d < 8; ++d)
#pragma unroll
    for (int r = 0; r < 4; ++r) {
      const float v = acc[d][r] / lrun[r];
      op[(long)(quad * 4 + r) * 2048 + d * 16 + l16] = f2bf(v);
    }
}

extern "C" void kernel_launch(void* const* d_in, const int* in_sizes, int n_in,
                              void* d_out, int out_size, void* d_ws, size_t ws_size,
                              hipStream_t stream) {
  const float* hidden = (const float*)d_in[0];  // [2,2048,2048]
  const float* w_qkv = (const float*)d_in[1];   // [6144,2048]
  const float* w_out = (const float*)d_in[2];   // [2048,2048]
  float* out = (float*)d_out;                   // [2,2048,2048] fp32
  char* ws = (char*)d_ws;

  // workspace layout (112 MB total, all 16B aligned)
  u16* hid_b  = (u16*)(ws + (size_t)0);          // hidden bf16
  u16* wqkv_b = (u16*)(ws + (size_t)16777216);   // w_qkv bf16
  u16* wout_b = (u16*)(ws + (size_t)41943040);   // w_out bf16
  u16* qb     = (u16*)(ws + (size_t)50331648);   // q (unroped) [B,H,S,D]
  u16* kb     = (u16*)(ws + (size_t)67108864);   // k (roped)   [B,H,S,D]
  u16* vb     = (u16*)(ws + (size_t)83886080);   // v^T [B,H,D,S]
  u16* ao     = (u16*)(ws + (size_t)100663296);  // attn out [B,S,E]

  cast3_kernel<<<24576, 256, 0, stream>>>(hidden, hid_b, 2097152,
                                          w_qkv, wqkv_b, 3145728,
                                          w_out, wout_b, 1048576);

  // qkv projection, fused split/transpose/k-rope epilogue
  gemm_bt_kernel<1><<<dim3(48, 32), 256, 0, stream>>>(hid_b, wqkv_b, 2048, 6144,
                                                      nullptr, qb, kb, vb);
  // causal flash attention (q-rope + scale in prologue)
  attn_kernel<<<1024, 256, 0, stream>>>(qb, kb, vb, ao);
  // output projection -> fp32
  gemm_bt_kernel<0><<<dim3(16, 32), 256, 0, stream>>>(ao, wout_b, 2048, 2048,
                                                      out, nullptr, nullptr, nullptr);
}

// Round 8
// 382.268 us; speedup vs baseline: 5.8526x; 1.2071x over previous
//
#include <hip/hip_runtime.h>

typedef unsigned short u16;
typedef unsigned int u32;
typedef __attribute__((ext_vector_type(4))) float f32x4;
typedef __attribute__((ext_vector_type(8))) short s16x8;
typedef __attribute__((ext_vector_type(4))) unsigned int u32x4;

#define DEVI static __device__ __forceinline__

// B=2, S=2048, E=2048, H=16, D=128, MP=4, local=512; qkv cols: [q(512) v(512) k(512)] x4
// k-rope fused into QKV-GEMM epilogue; q-rope (+ (1/sqrt(128))*log2(e) scale) fused into
// attention prologue; softmax in exp2 domain.

#define ROPE_C (-13.287712379549449f / 32.0f)  // -log2(10000)/32
#define QSCALE 0.12751743f                     // log2(e)/sqrt(128)

DEVI u16 f2bf(float f) {
  u32 u = __float_as_uint(f);
  return (u16)((u + 0x7FFFu + ((u >> 16) & 1u)) >> 16);  // round-to-nearest-even
}
DEVI float bf2f(u16 h) { return __uint_as_float(((u32)h) << 16); }

DEVI void async_copy16(const u16* g, u16* l) {
  // dest = wave-uniform LDS base + lane*16 (gfx950 global_load_lds_dwordx4)
  __builtin_amdgcn_global_load_lds((__attribute__((address_space(1))) void*)g,
                                   (__attribute__((address_space(3))) void*)l, 16, 0, 0);
}

// fused fp32->bf16 cast of all three inputs
__global__ __launch_bounds__(256) void cast3_kernel(
    const float* __restrict__ s0, u16* __restrict__ d0, int n0,
    const float* __restrict__ s1, u16* __restrict__ d1, int n1,
    const float* __restrict__ s2, u16* __restrict__ d2, int n2) {
  int i = blockIdx.x * 256 + threadIdx.x;
  const float* s;
  u16* d;
  if (i < n0) {
    s = s0; d = d0;
  } else if (i < n0 + n1) {
    s = s1; d = d1; i -= n0;
  } else if (i < n0 + n1 + n2) {
    s = s2; d = d2; i -= n0 + n1;
  } else {
    return;
  }
  const float4 v = ((const float4*)s)[i];
  ushort4 o;
  o.x = f2bf(v.x); o.y = f2bf(v.y); o.z = f2bf(v.z); o.w = f2bf(v.w);
  ((ushort4*)d)[i] = o;
}

// C[m,n] = sum_k A[m,k]*B[n,k]; A,B row-major bf16, K contiguous (B^T GEMM).
// 128x128 tile, BK=32, 4 waves 2x2 of 64x64, 16x16x32 MFMA, 4x4 frags/wave.
// R4 structure (best measured): A,B staged through 3-deep LDS via global_load_lds w16,
// XOR-swizzled, vmcnt(4) + raw s_barrier in steady state. Inline single-site epilogue.
// EPI=0: C fp32 store. EPI=1: scatter qkv -> q[B,H,S,D], k(roped)[B,H,S,D], v^T[B,H,D,S].
template <int EPI>
__global__ __launch_bounds__(256, 3) void gemm_bt_kernel(
    const u16* __restrict__ A, const u16* __restrict__ Bm, int K, int N,
    float* __restrict__ C, u16* __restrict__ qo, u16* __restrict__ ko, u16* __restrict__ vo) {
  __shared__ __attribute__((aligned(16))) u16 As[3][128 * 32];  // 8KB each
  __shared__ __attribute__((aligned(16))) u16 Bs[3][128 * 32];  // 8KB each
  const int tid = threadIdx.x;
  const int w = tid >> 6, lane = tid & 63;
  const int quad = lane >> 4, l16 = lane & 15;
  const int wrow = (w >> 1) * 64, wcol = (w & 1) * 64;
  const long tileM = (long)blockIdx.y * 128;
  const long tileN = (long)blockIdx.x * 128;

  f32x4 acc[4][4];
#pragma unroll
  for (int i = 0; i < 4; ++i)
#pragma unroll
    for (int j = 0; j < 4; ++j) acc[i][j] = f32x4{0.f, 0.f, 0.f, 0.f};

  // staging: wave w covers tile rows [w*32, w*32+32) in two 16-row chunks.
  const u16* aptr[2];
  const u16* bptr[2];
  int ldso[2];
#pragma unroll
  for (int c = 0; c < 2; ++c) {
    const int r0 = (w * 2 + c) * 16;
    const int row = r0 + (lane >> 2);
    const int colsw = (((lane & 3) ^ ((row >> 1) & 3)) << 3);
    aptr[c] = A + (tileM + row) * (long)K + colsw;
    bptr[c] = Bm + (tileN + row) * (long)K + colsw;
    ldso[c] = r0 * 32;
  }

  auto stage = [&](int k0, int buf) {
#pragma unroll
    for (int c = 0; c < 2; ++c) {
      async_copy16(aptr[c] + k0, &As[buf][ldso[c]]);
      async_copy16(bptr[c] + k0, &Bs[buf][ldso[c]]);
    }
  };

  stage(0, 0);
  stage(32, 1);

  const int psw = (quad ^ ((l16 >> 1) & 3)) << 3;  // read-side swizzle (lane-constant)

  int bt = 0;
  for (int k0 = 0; k0 < K; k0 += 32) {
    if (k0 + 32 < K)
      __builtin_amdgcn_s_waitcnt(0x0f74);  // vmcnt(4): tile t landed, t+1 in flight
    else
      __builtin_amdgcn_s_waitcnt(0x0f70);  // last tile: vmcnt(0)
    __builtin_amdgcn_s_barrier();          // raw barrier: no compiler-forced drain
    if (k0 + 64 < K) stage(k0 + 64, bt == 0 ? 2 : bt - 1);

    s16x8 af[4], bfr[4];
#pragma unroll
    for (int i = 0; i < 4; ++i)
      af[i] = *(const s16x8*)(&As[bt][(wrow + i * 16 + l16) * 32 + psw]);
#pragma unroll
    for (int j = 0; j < 4; ++j)
      bfr[j] = *(const s16x8*)(&Bs[bt][(wcol + j * 16 + l16) * 32 + psw]);
#pragma unroll
    for (int i = 0; i < 4; ++i)
#pragma unroll
      for (int j = 0; j < 4; ++j)
        acc[i][j] = __builtin_amdgcn_mfma_f32_16x16x32_bf16(af[i], bfr[j], acc[i][j], 0, 0, 0);
    bt = bt == 2 ? 0 : bt + 1;
  }

  // ---- inline epilogue (single call site; acc stays in registers) ----
  const int b = (int)(tileM >> 11);  // 128-row tile never straddles batch
#pragma unroll
  for (int i = 0; i < 4; ++i) {
#pragma unroll
    for (int j = 0; j < 4; ++j) {
      const int rowb = (int)((tileM + wrow + i * 16 + quad * 4) & 2047);  // s of reg 0
      if (EPI == 0) {
#pragma unroll
        for (int r = 0; r < 4; ++r) {
          const long row = tileM + wrow + i * 16 + quad * 4 + r;
          C[row * N + tileN + wcol + j * 16 + l16] = acc[i][j][r];
        }
      } else {
        const long col0 = tileN + wcol + j * 16;  // wave-uniform base col of this frag
        const int mp = (int)(col0 / 1536);
        const int cc0 = (int)(col0 - (long)mp * 1536);
        const int part = cc0 >> 9;     // 0:q 1:v 2:k (uniform per frag)
        const int idx0 = cc0 & 511;
        const int head = mp * 4 + (idx0 >> 7);
        const int dim0 = idx0 & 127;
        const int dim = dim0 + l16;
        const long bh = (long)(b * 16 + head);
        if (part == 1) {
#pragma unroll
          for (int r = 0; r < 4; ++r)
            vo[(bh * 128 + dim) * 2048 + rowb + r] = f2bf(acc[i][j][r]);  // v^T
        } else {
          float y[4];
          if (part == 2 && dim0 < 64) {
            // k-rope: pair partner is adjacent lane (col parity == l16 parity)
            const int jj = dim >> 1;
            const float inv = exp2f((float)jj * ROPE_C);
#pragma unroll
            for (int r = 0; r < 4; ++r) {
              const float v = acc[i][j][r];
              const float pv = __shfl_xor(v, 1, 64);
              const float ang = (float)(rowb + r) * inv;
              const float sn = __sinf(ang), cs = __cosf(ang);
              y[r] = (l16 & 1) ? (v * cs + pv * sn) : (v * cs - pv * sn);
            }
          } else {
#pragma unroll
            for (int r = 0; r < 4; ++r) y[r] = acc[i][j][r];
          }
          u16* dst = (part == 0) ? qo : ko;
#pragma unroll
          for (int r = 0; r < 4; ++r)
            dst[(bh * 2048 + rowb + r) * 128 + dim] = f2bf(y[r]);
        }
      }
    }
  }
}

// Flash attention v4: swapped-operand design. Block = 64 q rows (4 waves x 16 rows),
// 32-key LDS tiles (4 blocks/CU). S^T = K*Q^T (A=K, B=Q): each lane holds 8 scores of
// ONE q-row (keys in regs) -> softmax reduce = in-lane + 2 shfl; m/l scalars per lane;
// P enters PV as B-operand via an 8-shfl quad-exchange (no LDS round-trip);
// PV = V^T*P gives out^T whose stores vectorize as ushort4. Heavy-first grid.
__global__ __launch_bounds__(256, 4) void attn_kernel(
    const u16* __restrict__ q, const u16* __restrict__ k,
    const u16* __restrict__ vT, u16* __restrict__ out) {
  __shared__ __attribute__((aligned(16))) u16 Ks[2][32 * 128];  // 8KB each
  __shared__ __attribute__((aligned(16))) u16 Vs[2][128 * 32];  // 8KB each
  const int tid = threadIdx.x;
  const int w = tid >> 6, lane = tid & 63;
  const int quad = lane >> 4, l16 = lane & 15;
  const int qt = 31 - (blockIdx.x >> 5);  // heavy tiles dispatched first
  const int bh = blockIdx.x & 31;
  const int qbase = qt * 64 + w * 16;

  const u16* qp = q + ((long)bh * 2048 + qbase) * 128;
  const u16* kp = k + (long)bh * 2048 * 128;
  const u16* vp = vT + (long)bh * 128 * 2048;

  // Q B-frag: Q[n=l16][kdim = c*32 + quad*8 + j], roped + scaled in fp32
  const float spos = (float)(qbase + l16);
  s16x8 qf[4];
#pragma unroll
  for (int c = 0; c < 4; ++c) {
    const s16x8 raw = *(const s16x8*)(qp + l16 * 128 + c * 32 + quad * 8);
    s16x8 ov;
    if (c < 2) {  // dims < 64: rotate pairs (in-lane: 2m, 2m+1)
#pragma unroll
      for (int m = 0; m < 4; ++m) {
        const int jj = c * 16 + quad * 4 + m;
        const float inv = exp2f((float)jj * ROPE_C);
        const float ang = spos * inv;
        const float sn = __sinf(ang), cs = __cosf(ang);
        const float x0 = bf2f((u16)raw[2 * m]), x1 = bf2f((u16)raw[2 * m + 1]);
        ov[2 * m] = (short)f2bf((x0 * cs - x1 * sn) * QSCALE);
        ov[2 * m + 1] = (short)f2bf((x1 * cs + x0 * sn) * QSCALE);
      }
    } else {      // dims >= 64: pass-through, scale only
#pragma unroll
      for (int e = 0; e < 8; ++e) ov[e] = (short)f2bf(bf2f((u16)raw[e]) * QSCALE);
    }
    qf[c] = ov;
  }

  f32x4 acc[8];  // out^T: acc[dd] rows = dims dd*16+quad*4+r, col = q-row l16
#pragma unroll
  for (int d = 0; d < 8; ++d) acc[d] = f32x4{0.f, 0.f, 0.f, 0.f};
  float mrun = -1e30f, lrun = 0.f;  // per-lane scalars (q-row = qbase+l16)

  // stage one 32-key tile: wave w stages keys [w*8,w*8+8) and dims [w*32,w*32+32)
  auto stage = [&](int k0, int buf) {
    const int ko = lane >> 4, cl = lane & 15;
#pragma unroll
    for (int i = 0; i < 2; ++i) {
      const int keyt = w * 8 + i * 4;
      const int key = keyt + ko;
      async_copy16(kp + (long)(k0 + key) * 128 + ((cl ^ (key & 15)) << 3),
                   &Ks[buf][keyt * 128]);
    }
    const int ld = lane >> 2, c4 = lane & 3;
#pragma unroll
    for (int i = 0; i < 2; ++i) {
      const int db = w * 32 + i * 16;
      const int d = db + ld;
      async_copy16(vp + (long)d * 2048 + k0 + ((c4 ^ ((d >> 1) & 3)) << 3),
                   &Vs[buf][db * 32]);
    }
  };

  stage(0, 0);

  const int nt = 2 * qt + 2;
  for (int t = 0; t < nt; ++t) {
    const int k0 = t * 32;
    const u16* Ksc = Ks[t & 1];
    const u16* Vsc = Vs[t & 1];
    __builtin_amdgcn_s_waitcnt(0x0f70);  // vmcnt(0) only: my tile-t DMA done
    __syncthreads();                     // all waves' DMA done; prev buf free
    if (t + 1 < nt) stage(k0 + 32, (t + 1) & 1);

    // S^T = K*Q^T: sc[g] rows = keys k0+g*16+quad*4+r, col = q-row l16
    f32x4 sc[2];
#pragma unroll
    for (int g = 0; g < 2; ++g) {
      sc[g] = f32x4{0.f, 0.f, 0.f, 0.f};
#pragma unroll
      for (int c = 0; c < 4; ++c) {
        const s16x8 kf = *(const s16x8*)(
            &Ksc[(g * 16 + l16) * 128 + ((((c << 2) + quad) ^ l16) << 3)]);
        sc[g] = __builtin_amdgcn_mfma_f32_16x16x32_bf16(kf, qf[c], sc[g], 0, 0, 0);
      }
    }
    if (k0 + 31 > qbase) {  // tile may cross the diagonal (wave-uniform branch)
      const int qrow = qbase + l16;
#pragma unroll
      for (int g = 0; g < 2; ++g) {
        const int keyb = k0 + g * 16 + quad * 4;
#pragma unroll
        for (int r = 0; r < 4; ++r)
          if (keyb + r > qrow) sc[g][r] = -1e30f;
      }
    }
    // online softmax (exp2 domain): keys live in regs + across quads
    float mx = fmaxf(fmaxf(fmaxf(sc[0][0], sc[0][1]), fmaxf(sc[0][2], sc[0][3])),
                     fmaxf(fmaxf(sc[1][0], sc[1][1]), fmaxf(sc[1][2], sc[1][3])));
    mx = fmaxf(mx, __shfl_xor(mx, 16, 64));
    mx = fmaxf(mx, __shfl_xor(mx, 32, 64));
    const float mnew = fmaxf(mrun, mx);
    const float alpha = exp2f(mrun - mnew);
    mrun = mnew;
    float p[2][4];
    float sm = 0.f;
#pragma unroll
    for (int g = 0; g < 2; ++g)
#pragma unroll
      for (int r = 0; r < 4; ++r) { p[g][r] = exp2f(sc[g][r] - mnew); sm += p[g][r]; }
    sm += __shfl_xor(sm, 16, 64);
    sm += __shfl_xor(sm, 32, 64);
    lrun = lrun * alpha + sm;
#pragma unroll
    for (int d = 0; d < 8; ++d)
#pragma unroll
      for (int r = 0; r < 4; ++r) acc[d][r] *= alpha;

    // quad-exchange P (S^T C-layout) -> PV B-frag P[n=qrow l16][k=key quad*8+j].
    // dest (quad,j): src lane 32*(quad&1)+l16 (+16 for j>=4), frag g=quad>>1, reg j&3.
    u32 pk[2][2];
#pragma unroll
    for (int g = 0; g < 2; ++g) {
      pk[g][0] = (u32)f2bf(p[g][0]) | ((u32)f2bf(p[g][1]) << 16);
      pk[g][1] = (u32)f2bf(p[g][2]) | ((u32)f2bf(p[g][3]) << 16);
    }
    const int la = ((quad & 1) << 5) + l16;
    const int lb = la + 16;
    const u32 a0 = (u32)__shfl((int)pk[0][0], la, 64);
    const u32 a1 = (u32)__shfl((int)pk[0][1], la, 64);
    const u32 a2 = (u32)__shfl((int)pk[0][0], lb, 64);
    const u32 a3 = (u32)__shfl((int)pk[0][1], lb, 64);
    const u32 b0 = (u32)__shfl((int)pk[1][0], la, 64);
    const u32 b1 = (u32)__shfl((int)pk[1][1], la, 64);
    const u32 b2 = (u32)__shfl((int)pk[1][0], lb, 64);
    const u32 b3 = (u32)__shfl((int)pk[1][1], lb, 64);
    const bool hi = quad >= 2;
    const u32x4 pw = {hi ? b0 : a0, hi ? b1 : a1, hi ? b2 : a2, hi ? b3 : a3};
    const s16x8 pf = __builtin_bit_cast(s16x8, pw);

    // PV: out^T += V^T * P  (A = V^T[m=dim][k=key], B = P[n=qrow][k=key])
#pragma unroll
    for (int dd = 0; dd < 8; ++dd) {
      const s16x8 vf = *(const s16x8*)(
          &Vsc[(dd * 16 + l16) * 32 + ((quad ^ ((l16 >> 1) & 3)) << 3)]);
      acc[dd] = __builtin_amdgcn_mfma_f32_16x16x32_bf16(vf, pf, acc[dd], 0, 0, 0);
    }
  }

  // epilogue: lane l16 owns q-row qbase+l16; dims dd*16+quad*4+r -> ushort4 stores
  const int b = bh >> 4, h = bh & 15;
  u16* op = out + ((long)b * 2048 + qbase + l16) * 2048 + h * 128;
  const float inv_l = 1.0f / lrun;
#pragma unroll
  for (int dd = 0; dd < 8; ++dd) {
    ushort4 o4;
    o4.x = f2bf(acc[dd][0] * inv_l);
    o4.y = f2bf(acc[dd][1] * inv_l);
    o4.z = f2bf(acc[dd][2] * inv_l);
    o4.w = f2bf(acc[dd][3] * inv_l);
    *(ushort4*)(op + dd * 16 + quad * 4) = o4;
  }
}

extern "C" void kernel_launch(void* const* d_in, const int* in_sizes, int n_in,
                              void* d_out, int out_size, void* d_ws, size_t ws_size,
                              hipStream_t stream) {
  const float* hidden = (const float*)d_in[0];  // [2,2048,2048]
  const float* w_qkv = (const float*)d_in[1];   // [6144,2048]
  const float* w_out = (const float*)d_in[2];   // [2048,2048]
  float* out = (float*)d_out;                   // [2,2048,2048] fp32
  char* ws = (char*)d_ws;

  // workspace layout (112 MB total, all 16B aligned)
  u16* hid_b  = (u16*)(ws + (size_t)0);          // hidden bf16
  u16* wqkv_b = (u16*)(ws + (size_t)16777216);   // w_qkv bf16
  u16* wout_b = (u16*)(ws + (size_t)41943040);   // w_out bf16
  u16* qb     = (u16*)(ws + (size_t)50331648);   // q (unroped) [B,H,S,D]
  u16* kb     = (u16*)(ws + (size_t)67108864);   // k (roped)   [B,H,S,D]
  u16* vb     = (u16*)(ws + (size_t)83886080);   // v^T [B,H,D,S]
  u16* ao     = (u16*)(ws + (size_t)100663296);  // attn out [B,S,E]

  cast3_kernel<<<24576, 256, 0, stream>>>(hidden, hid_b, 2097152,
                                          w_qkv, wqkv_b, 3145728,
                                          w_out, wout_b, 1048576);

  // qkv projection, fused split/transpose/k-rope epilogue
  gemm_bt_kernel<1><<<dim3(48, 32), 256, 0, stream>>>(hid_b, wqkv_b, 2048, 6144,
                                                      nullptr, qb, kb, vb);
  // causal flash attention (q-rope + scale in prologue)
  attn_kernel<<<1024, 256, 0, stream>>>(qb, kb, vb, ao);
  // output projection -> fp32
  gemm_bt_kernel<0><<<dim3(16, 32), 256, 0, stream>>>(ao, wout_b, 2048, 2048,
                                                      out, nullptr, nullptr, nullptr);
}